// Round 18
// baseline (451.972 us; speedup 1.0000x reference)
//
#include <hip/hip_runtime.h>

// VQ-VAE vector quantizer. Round 18 (R17 retry — compile fix only).
// z: [16,64,32,32] f32, emb: [8192,64] f32. N=16384 pts, C=64, V=8192.
// out = [ z_q_st (1048576) | idx as f32 (16384) | vq_loss (1) ]
//
// R16: k1 parked at 42us; ~60us inferred in inter-kernel boundaries.
// R17/18: ONE kernel, 512 blocks x 256 thr, launch_bounds(256,4) ->
// capacity 1024 >= 512 = co-residency with 2x margin. Phases PRE -> SCORE
// (2 splits/block, A loaded once) -> MERGE -> RESCUE (2-D tasks, per-group
// completion) -> QUANT -> loss, via spin barriers (device-scope
// release/acquire). Counters zeroed by one hipMemsetAsync node.

typedef _Float16 half8 __attribute__((ext_vector_type(8)));
typedef float f32x4 __attribute__((ext_vector_type(4)));

#define N_PTS 16384
#define SPLITS 16
#define THR16 0.08f   // fp16-score error bound (10 sigma), validated R3-R16
#define GRID 512

__device__ __forceinline__ void dbar(int* ctr) {
  __syncthreads();
  if (threadIdx.x == 0) {
    __threadfence();
    __hip_atomic_fetch_add(ctr, 1, __ATOMIC_RELEASE, __HIP_MEMORY_SCOPE_AGENT);
    while (__hip_atomic_load(ctr, __ATOMIC_ACQUIRE, __HIP_MEMORY_SCOPE_AGENT) < GRID)
      __builtin_amdgcn_s_sleep(32);
  }
  __syncthreads();
}

__global__ __launch_bounds__(256, 4) void k_fused(
    const float* __restrict__ z, const float* __restrict__ emb,
    float* __restrict__ out, float* __restrict__ hneg,
    unsigned short* __restrict__ e16, float* __restrict__ embT,
    float2* __restrict__ psp, int* __restrict__ idxf, int* __restrict__ list,
    unsigned long long* __restrict__ rpack, int* __restrict__ gdone,
    float* __restrict__ psum, int* __restrict__ ctrs,
    float* __restrict__ out_idx, float* __restrict__ out_loss) {
  __shared__ float hs[512];
  __shared__ float zsT[64][8];
  __shared__ int pn[8];
  __shared__ unsigned long long red[4][8];
  __shared__ int lastS;
  __shared__ float wsum[4];

  const int tid = threadIdx.x;
  const int lane = tid & 63;
  const int wid = tid >> 6;
  const int bid = blockIdx.x;

  // ================= PRE: emb -> e16 swizzled + embT + hneg =================
  if (bid < 128) {
    int t = bid * 256 + tid;               // 32768 threads: 4 per code row
    int v = t >> 2, part = t & 3;
    const float4* e4 = (const float4*)(emb + v * 64 + part * 16);
    float row[16];
    float s = 0.f;
#pragma unroll
    for (int i = 0; i < 4; ++i) {
      float4 a = e4[i];
      row[i * 4 + 0] = a.x; row[i * 4 + 1] = a.y;
      row[i * 4 + 2] = a.z; row[i * 4 + 3] = a.w;
      s += a.x * a.x + a.y * a.y + a.z * a.z + a.w * a.w;
    }
    s += __shfl_xor(s, 1);
    s += __shfl_xor(s, 2);
    unsigned short* base = e16 + (v >> 4) * 1024 + (v & 15) * 8;
#pragma unroll
    for (int g = 0; g < 2; ++g) {
      int c8 = part * 2 + g;
      half8 o;
#pragma unroll
      for (int j = 0; j < 8; ++j) o[j] = (_Float16)row[g * 8 + j];
      *(half8*)(base + (c8 >> 2) * 512 + (c8 & 3) * 128) = o;
    }
#pragma unroll
    for (int i = 0; i < 16; ++i) embT[(part * 16 + i) * 8192 + v] = row[i];
    if (part == 0) hneg[v] = -0.5f * s;
  }
  dbar(ctrs + 1);

  // ================= SCORE: MFMA + packed-index top-2 =================
  // block handles point-tile bx for splits sb and sb+8; A loaded once.
  {
    const int bx = bid & 63;
    const int sb = bid >> 6;               // 0..7
    const int cl = lane & 15;
    const int gq = lane >> 4;
    const int n0 = bx * 256 + wid * 64;
    const int b = n0 >> 10;
    const int hw0 = n0 & 1023;

    half8 A[4][2];
    {
      const float* zb = z + b * 65536 + hw0 + cl;
#pragma unroll
      for (int pt = 0; pt < 4; ++pt)
#pragma unroll
        for (int H = 0; H < 2; ++H) {
          half8 a;
#pragma unroll
          for (int j = 0; j < 8; ++j)
            a[j] = (_Float16)zb[pt * 16 + (H * 32 + gq * 8 + j) * 1024];
          A[pt][H] = a;
        }
    }

    for (int sp = 0; sp < 2; ++sp) {
      const int split = sb + sp * 8;
      const int vbase = split * 512;
      __syncthreads();                     // prior hs readers done
      *(float2*)&hs[tid * 2] = *(const float2*)(hneg + vbase + tid * 2);
      __syncthreads();

      float s1[4][4], s2[4][4];
#pragma unroll
      for (int pt = 0; pt < 4; ++pt)
#pragma unroll
        for (int r = 0; r < 4; ++r) { s1[pt][r] = -3.0e38f; s2[pt][r] = -3.0e38f; }

      const unsigned short* bp = e16 + vbase * 64 + lane * 8;
      int idxb = 8191 - (vbase + cl);

      half8 B0 = *(const half8*)bp;
      half8 B1 = *(const half8*)(bp + 512);

      for (int T = 0; T < 32; ++T) {
        half8 nB0, nB1;
        if (T < 31) {
          nB0 = *(const half8*)(bp + 1024);
          nB1 = *(const half8*)(bp + 1536);
        }
        const float nh = hs[T * 16 + cl];
        f32x4 C0;
        C0[0] = nh; C0[1] = nh; C0[2] = nh; C0[3] = nh;

#pragma unroll
        for (int pt = 0; pt < 4; ++pt) {
          f32x4 acc = __builtin_amdgcn_mfma_f32_16x16x32_f16(A[pt][0], B0, C0, 0, 0, 0);
          acc = __builtin_amdgcn_mfma_f32_16x16x32_f16(A[pt][1], B1, acc, 0, 0, 0);
#pragma unroll
          for (int r = 0; r < 4; ++r) {
            unsigned u = (__float_as_uint(acc[r]) & 0xFFFFE000u) | (unsigned)idxb;
            float p = __uint_as_float(u);
            s2[pt][r] = __builtin_amdgcn_fmed3f(p, s1[pt][r], s2[pt][r]);
            s1[pt][r] = fmaxf(s1[pt][r], p);
          }
        }
        idxb -= 16;
        B0 = nB0; B1 = nB1;
        bp += 1024;
      }

#pragma unroll
      for (int off = 8; off >= 1; off >>= 1) {
#pragma unroll
        for (int pt = 0; pt < 4; ++pt)
#pragma unroll
          for (int r = 0; r < 4; ++r) {
            float os = __shfl_xor(s1[pt][r], off);
            float o2 = __shfl_xor(s2[pt][r], off);
            s2[pt][r] = fmaxf(fmaxf(s2[pt][r], o2), fminf(s1[pt][r], os));
            s1[pt][r] = fmaxf(s1[pt][r], os);
          }
      }

      if (cl == 0) {
#pragma unroll
        for (int pt = 0; pt < 4; ++pt)
#pragma unroll
          for (int r = 0; r < 4; ++r) {
            int n = n0 + pt * 16 + gq * 4 + r;
            float2 o; o.x = s1[pt][r]; o.y = s2[pt][r];
            psp[split * N_PTS + n] = o;
          }
      }
    }
  }
  dbar(ctrs + 2);

  // ================= MERGE: splits -> idx, margin -> list =================
  if (tid < 32) {
    int n = bid * 32 + tid;
    float S1 = -3.0e38f, S2 = -3.0e38f;
#pragma unroll
    for (int s = 0; s < SPLITS; ++s) {
      float2 a = psp[s * N_PTS + n];
      if (a.x > S1) { S2 = fmaxf(fmaxf(S2, a.y), S1); S1 = a.x; }
      else          { S2 = fmaxf(S2, a.x); }
    }
    int I1 = 8191 - (int)(__float_as_uint(S1) & 0x1FFFu);
    idxf[n] = I1;
    out_idx[n] = (float)I1;
    float q = fmaxf(fabsf(S1), fabsf(S2)) * 0.0009765625f;
    if (S1 - S2 < THR16 + q) {
      int p = __hip_atomic_fetch_add(ctrs, 1, __ATOMIC_RELAXED,
                                     __HIP_MEMORY_SCOPE_AGENT);
      list[p] = n;
    }
  }
  dbar(ctrs + 3);

  // ================= RESCUE: 2-D tasks, per-group completion =================
  {
    const int count = __hip_atomic_load(ctrs, __ATOMIC_RELAXED,
                                        __HIP_MEMORY_SCOPE_AGENT);
    const int ntasks = ((count + 7) >> 3) << 3;

    for (int task = bid; task < ntasks; task += GRID) {
      const int grp = task >> 3, chunk = task & 7;
      const int base = grp * 8;
      const int P = min(8, count - base);
      __syncthreads();
      if (tid < 8) pn[tid] = list[base + min(tid, P - 1)];
      __syncthreads();
#pragma unroll
      for (int i = tid; i < 512; i += 256) {
        int p = i >> 6, c = i & 63;
        int n = pn[p];
        zsT[c][p] = z[(n >> 10) * 65536 + c * 1024 + (n & 1023)];
      }
      __syncthreads();

      float d[32];
#pragma unroll
      for (int i = 0; i < 32; ++i) d[i] = 0.f;

      const float4* ep = (const float4*)embT + chunk * 256 + tid;
      float4 cur = ep[0];
      for (int c = 0; c < 64; ++c) {
        float4 nxt;
        if (c < 63) nxt = ep[(c + 1) * 2048];
        float4 zpA = *(const float4*)&zsT[c][0];
        float4 zpB = *(const float4*)&zsT[c][4];
#pragma unroll
        for (int k = 0; k < 4; ++k) {
          float e = (k == 0) ? cur.x : (k == 1) ? cur.y : (k == 2) ? cur.z : cur.w;
          float* dp = d + k * 8;
          dp[0] = fmaf(e, zpA.x, dp[0]); dp[1] = fmaf(e, zpA.y, dp[1]);
          dp[2] = fmaf(e, zpA.z, dp[2]); dp[3] = fmaf(e, zpA.w, dp[3]);
          dp[4] = fmaf(e, zpB.x, dp[4]); dp[5] = fmaf(e, zpB.y, dp[5]);
          dp[6] = fmaf(e, zpB.z, dp[6]); dp[7] = fmaf(e, zpB.w, dp[7]);
        }
        if (c < 63) cur = nxt;
      }

      float4 hv = *(const float4*)(hneg + chunk * 1024 + tid * 4);
      unsigned long long best[8];
#pragma unroll
      for (int p = 0; p < 8; ++p) best[p] = 0ull;
#pragma unroll
      for (int k = 0; k < 4; ++k) {
        float hk = (k == 0) ? hv.x : (k == 1) ? hv.y : (k == 2) ? hv.z : hv.w;
        unsigned tag = (unsigned)(8191 - (chunk * 1024 + tid * 4 + k));
#pragma unroll
        for (int p = 0; p < 8; ++p) {
          float sc = d[k * 8 + p] + hk;
          unsigned u = __float_as_uint(sc);
          unsigned sb2 = (u & 0x80000000u) ? ~u : (u | 0x80000000u);
          unsigned long long pk = ((unsigned long long)sb2 << 32) | tag;
          best[p] = (pk > best[p]) ? pk : best[p];
        }
      }
#pragma unroll
      for (int off = 32; off >= 1; off >>= 1) {
#pragma unroll
        for (int p = 0; p < 8; ++p) {
          unsigned long long o = __shfl_xor(best[p], off);
          best[p] = (o > best[p]) ? o : best[p];
        }
      }
      if (lane == 0)
#pragma unroll
        for (int p = 0; p < 8; ++p) red[wid][p] = best[p];
      __syncthreads();
      if (tid < 8) {
        unsigned long long bmax = red[0][tid];
#pragma unroll
        for (int w = 1; w < 4; ++w) bmax = (red[w][tid] > bmax) ? red[w][tid] : bmax;
        if (tid < P) atomicMax(&rpack[base + tid], bmax);
      }
      __syncthreads();
      if (tid == 0) {
        lastS = (__hip_atomic_fetch_add(&gdone[grp * 16], 1, __ATOMIC_ACQ_REL,
                                        __HIP_MEMORY_SCOPE_AGENT) == 7) ? 1 : 0;
      }
      __syncthreads();
      if (lastS && tid < P) {
        unsigned long long pk = __hip_atomic_load(&rpack[base + tid],
                                                  __ATOMIC_RELAXED,
                                                  __HIP_MEMORY_SCOPE_AGENT);
        int code = 8191 - (int)(pk & 0xFFFFFFFFull);
        int n = pn[tid];
        idxf[n] = code;
        out_idx[n] = (float)code;
      }
    }
  }
  dbar(ctrs + 4);

  // ================= QUANT: gather, ST out, loss =================
  {
    float val = 0.f;
#pragma unroll
    for (int it = 0; it < 2; ++it) {
      int t = it * 131072 + bid * 256 + tid;   // 262144 float4 slots
      int g = t * 4;
      int b = g >> 16;
      int c = (g >> 10) & 63;
      int hw = g & 1023;
      int n = (b << 10) | hw;
      float4 zv = *(const float4*)(z + g);
      int4 iv = *(const int4*)(idxf + n);
      float q0 = emb[iv.x * 64 + c];
      float q1 = emb[iv.y * 64 + c];
      float q2 = emb[iv.z * 64 + c];
      float q3 = emb[iv.w * 64 + c];
      float d0 = q0 - zv.x, d1 = q1 - zv.y, d2 = q2 - zv.z, d3 = q3 - zv.w;
      float4 o;
      o.x = zv.x + d0; o.y = zv.y + d1; o.z = zv.z + d2; o.w = zv.w + d3;
      *(float4*)(out + g) = o;
      val += d0 * d0 + d1 * d1 + d2 * d2 + d3 * d3;
    }
#pragma unroll
    for (int off = 32; off >= 1; off >>= 1) val += __shfl_down(val, off);
    __syncthreads();
    if (lane == 0) wsum[wid] = val;
    __syncthreads();
    if (tid == 0)
      psum[bid] = wsum[0] + wsum[1] + wsum[2] + wsum[3];
  }

  // ================= final loss (block 0 after all psum) =================
  __syncthreads();
  if (tid == 0) {
    __threadfence();
    __hip_atomic_fetch_add(ctrs + 5, 1, __ATOMIC_RELEASE, __HIP_MEMORY_SCOPE_AGENT);
  }
  if (bid == 0) {
    if (tid == 0) {
      while (__hip_atomic_load(ctrs + 5, __ATOMIC_ACQUIRE,
                               __HIP_MEMORY_SCOPE_AGENT) < GRID)
        __builtin_amdgcn_s_sleep(32);
    }
    __syncthreads();
    float v = psum[tid] + psum[tid + 256];
#pragma unroll
    for (int off = 32; off >= 1; off >>= 1) v += __shfl_down(v, off);
    __syncthreads();
    if (lane == 0) wsum[wid] = v;
    __syncthreads();
    if (tid == 0)
      out_loss[0] = 1.25f * (wsum[0] + wsum[1] + wsum[2] + wsum[3]) * (1.0f / 1048576.0f);
  }
}

extern "C" void kernel_launch(void* const* d_in, const int* in_sizes, int n_in,
                              void* d_out, int out_size, void* d_ws, size_t ws_size,
                              hipStream_t stream) {
  const float* z   = (const float*)d_in[0];
  const float* emb = (const float*)d_in[1];
  float* out = (float*)d_out;
  float* ws  = (float*)d_ws;

  float* hneg = ws;                                    // 8192
  unsigned short* e16 = (unsigned short*)(ws + 8192);  // 524288 halfs = 262144 f
  float* embT = ws + 8192 + 262144;                    // 524288
  float2* psp = (float2*)(embT + 524288);              // 16*16384 float2 = 524288 f
  int* idxf  = (int*)(psp + SPLITS * N_PTS);           // 16384
  int* list  = idxf + N_PTS;                           // 16384
  float* psum = (float*)(list + N_PTS);                // 512
  int* ctrs  = (int*)(psum + 512);                     // 16 ints
  unsigned long long* rpack = (unsigned long long*)(ctrs + 16);  // 16384 u64
  int* gdone = (int*)(rpack + N_PTS);                  // 2048*16 ints

  float* out_idx  = out + 1048576;
  float* out_loss = out + 1048576 + 16384;

  // zero ctrs + rpack + gdone in one memset node
  size_t zbytes = 16 * 4 + (size_t)N_PTS * 8 + 2048 * 16 * 4;
  (void)hipMemsetAsync(ctrs, 0, zbytes, stream);

  k_fused<<<GRID, 256, 0, stream>>>(z, emb, out, hneg, e16, embT, psp, idxf,
                                    list, rpack, gdone, psum, ctrs,
                                    out_idx, out_loss);
}